// Round 2
// baseline (374.106 us; speedup 1.0000x reference)
//
#include <hip/hip_runtime.h>
#include <hip/hip_bf16.h>

// Problem constants
#define B_   32
#define S_   512
#define NB_  20
#define EMB_ 128
#define VOC_ 40000

typedef float f32x4 __attribute__((ext_vector_type(4)));
typedef _Float16 f16x8 __attribute__((ext_vector_type(8)));
typedef __fp16 fp16x2 __attribute__((ext_vector_type(2)));

union FragH { uint4 u; f16x8 h; };
union H2 { fp16x2 h; unsigned u; };

__device__ __forceinline__ unsigned pk2(float a, float b){
  H2 t; t.h = __builtin_amdgcn_cvt_pkrtz(a, b);
  return t.u;
}
__device__ __forceinline__ unsigned short f2h(float x){
  _Float16 h = (_Float16)x;   // RNE
  return __builtin_bit_cast(unsigned short, h);
}
__device__ __forceinline__ float tanh_fast(float x){
  float xx = fminf(fmaxf(x, -15.f), 15.f);
  float e = __expf(2.f*xx);
  return (e-1.f)/(e+1.f);
}

// LDS fragment-slot swizzle: element (row,k) -> chunk/halfword
//   mt=row>>4, r=row&15, kg=k>>5, s2=(k>>3)&3, off=k&7
//   slot = s2<<4 | ((r ^ s2 ^ ((kg&1)<<2)) & 15)
//   chunk = (mt*4+kg)*64 + slot ; halfword = chunk*8 + off
// Reader lane l for (mt,kc): s2=l>>4, r=l&15  -> one ds_read_b128.

// ---------------------------------------------------------------------------
// Prep: u, qc=u@C, tf=u@F, uh=u@H, kb=emb[keys]@Bm (fp32),
// plus fp16 B-operand fragments of A (K=128) and [D;E] (K=256).
// B-frag: chunk=((nt*KC+kc)*64+lane): n=nt*16+(lane&15), k=kc*32+(lane>>4)*8+j
// ---------------------------------------------------------------------------
__global__ __launch_bounds__(128) void prep_kernel(
    const int* __restrict__ queries, const int* __restrict__ keys,
    const float* __restrict__ emb, const float* __restrict__ mmask,
    const float* __restrict__ A, const float* __restrict__ Bm,
    const float* __restrict__ C, const float* __restrict__ D,
    const float* __restrict__ E, const float* __restrict__ F,
    const float* __restrict__ H,
    float* __restrict__ qc_w, float* __restrict__ tf_w,
    float* __restrict__ uh_w, float* __restrict__ kb_w,
    unsigned short* __restrict__ afrag, unsigned short* __restrict__ w2frag)
{
  int bid = blockIdx.x, tid = threadIdx.x;
  if (bid < 32) {
    __shared__ float ulds[128];
    int b = bid;
    float s = 0.f;
    for (int q=0;q<NB_;q++){
      int tok = queries[b*NB_+q];
      s += emb[tok*128+tid]*mmask[q*128+tid];
    }
    ulds[tid] = s;
    __syncthreads();
    float sq=0.f, sf=0.f, sh=0.f;
    for (int e=0;e<128;e++){
      float uv = ulds[e];
      sq += uv*C[e*128+tid];
      sf += uv*F[e*128+tid];
      sh += uv*H[e*128+tid];
    }
    qc_w[b*128+tid]=sq; tf_w[b*128+tid]=sf; uh_w[b*128+tid]=sh;
  } else if (bid < 52) {
    __shared__ float ek[128];
    int n = bid-32;
    int tok = keys[n];
    ek[tid] = emb[tok*128+tid];
    __syncthreads();
    float s=0.f;
    for (int e=0;e<128;e++) s += ek[e]*Bm[e*128+tid];
    kb_w[n*128+tid] = s;
  } else if (bid < 60) {
    // A fragments: nt=8, kc=4 -> 2048 chunks fp16
    int a = bid-52;
    for (int cc=0;cc<2;cc++){
      int c = (a*128+tid)*2+cc;
      int lane = c&63, kc = (c>>6)&3, nt = c>>8;
      int n2 = nt*16 + (lane&15);
      int k0 = kc*32 + (lane>>4)*8;
      alignas(16) unsigned short t[8];
      #pragma unroll
      for (int j=0;j<8;j++) t[j] = f2h(A[(k0+j)*128+n2]);
      *(uint4*)(afrag + c*8) = *(const uint4*)t;
    }
  } else {
    // W2=[D;E] fragments: nt=8, kc=8 -> 4096 chunks fp16
    int wb = bid-60;
    for (int cc=0;cc<2;cc++){
      int c = (wb*128+tid)*2+cc;
      int lane = c&63, kc = (c>>6)&7, nt = c>>9;
      int n2 = nt*16 + (lane&15);
      int k0 = kc*32 + (lane>>4)*8;
      alignas(16) unsigned short t[8];
      #pragma unroll
      for (int j=0;j<8;j++){
        int k = k0+j;
        float x = (k<128) ? D[k*128+n2] : E[(k-128)*128+n2];
        t[j] = f2h(x);
      }
      *(uint4*)(w2frag + c*8) = *(const uint4*)t;
    }
  }
}

// ---------------------------------------------------------------------------
// K2 (merged k2a+k2b): 4 (b,s) pairs/block.
// Phase 1: M=80,K=128,N=128 fp16 MFMA (ia) -> intr align/softmax -> tm.
// Phase 2: reuse LDS: A2=[tm|stories] (4 valid rows, K=256) @ [D;E] ->
//          talign = (mask!=0) ? mask*sum_i w_i tanh(td+te+tf) : -inf.
// tm stored to global as fp16 for K3.
// ---------------------------------------------------------------------------
__global__ __launch_bounds__(256) void k2_kernel(
    const float* __restrict__ mem, const unsigned short* __restrict__ afrag,
    const float* __restrict__ kb_w, const float* __restrict__ qc_w,
    const float* __restrict__ vvec,
    const float* __restrict__ stories, const unsigned short* __restrict__ w2frag,
    const float* __restrict__ tf_w, const float* __restrict__ wvec,
    const float* __restrict__ smask,
    unsigned short* __restrict__ tm_h, float* __restrict__ talign_w)
{
  __shared__ unsigned short mfr[5*4*64*8];   // 20KB; first 8KB reused as A2 frags
  __shared__ float alignP[4*80];
  __shared__ float aligns[80];
  __shared__ float attns[80];
  __shared__ float partial2[16];

  int g = blockIdx.x, tid = threadIdx.x;
  int b = g >> 7;   // 128 blocks per batch element

  // early: stories rows for this block (4 x 128), float2 per thread
  int p2 = tid>>6, e0 = (tid&63)*2;
  float2 sto = *(const float2*)(stories + ((size_t)(g*4+p2))*128 + e0);

  // stage: 10240 contiguous floats -> fp16, swizzled frag layout
  const float4* gm = (const float4*)(mem) + (size_t)g*2560;
  #pragma unroll
  for (int it=0; it<10; ++it){
    int i4 = tid + it*256;
    float4 d = gm[i4];
    int e4 = i4*4;
    int row = e4 >> 7;          // 0..79
    int k = e4 & 127;
    int mt = row>>4, r = row&15;
    int kg = k>>5, s2 = (k>>3)&3;
    int slot = (s2<<4) | ((r ^ s2 ^ ((kg&1)<<2)) & 15);
    int chunk = (mt*4+kg)*64 + slot;
    *(uint2*)(mfr + chunk*8 + (k&7)) = make_uint2(pk2(d.x,d.y), pk2(d.z,d.w));
  }
  __syncthreads();

  int w = tid>>6, lane = tid&63;
  int lo16 = lane & 15, hi16 = lane >> 4;

  {
    f32x4 acc[5][2];
    #pragma unroll
    for (int mt=0;mt<5;mt++){ acc[mt][0]=(f32x4)(0.f); acc[mt][1]=(f32x4)(0.f); }

    #pragma unroll
    for (int kc=0;kc<4;kc++){
      FragH b0, b1;
      b0.u = *(const uint4*)(afrag + ((size_t)((2*w)*4+kc)*64 + lane)*8);
      b1.u = *(const uint4*)(afrag + ((size_t)((2*w+1)*4+kc)*64 + lane)*8);
      int slot = (hi16<<4) | ((lo16 ^ hi16 ^ ((kc&1)<<2)) & 15);
      #pragma unroll
      for (int mt=0;mt<5;mt++){
        FragH a;
        a.u = *(const uint4*)(mfr + ((mt*4+kc)*64 + slot)*8);
        acc[mt][0] = __builtin_amdgcn_mfma_f32_16x16x32_f16(a.h, b0.h, acc[mt][0], 0,0,0);
        acc[mt][1] = __builtin_amdgcn_mfma_f32_16x16x32_f16(a.h, b1.h, acc[mt][1], 0,0,0);
      }
    }

    // epilogue: align[row] = sum_i v_i * tanh(ia + kb[n,i] + qc[b,i])
    #pragma unroll
    for (int mt=0;mt<5;mt++){
      #pragma unroll
      for (int r=0;r<4;r++){
        unsigned row = mt*16 + hi16*4 + r;
        unsigned p = row/20u;
        unsigned n = row - p*20u;
        float part = 0.f;
        #pragma unroll
        for (int t2=0;t2<2;t2++){
          int col = (2*w+t2)*16 + lo16;
          float z = acc[mt][t2][r] + kb_w[n*128+col] + qc_w[b*128+col];
          part += vvec[col]*tanh_fast(z);
        }
        part += __shfl_xor(part, 1);
        part += __shfl_xor(part, 2);
        part += __shfl_xor(part, 4);
        part += __shfl_xor(part, 8);
        if (lo16 == 0) alignP[w*80+row] = part;
      }
    }
  }
  __syncthreads();
  if (tid < 80){
    aligns[tid] = alignP[tid] + alignP[80+tid] + alignP[160+tid] + alignP[240+tid];
  }
  __syncthreads();
  if (tid < 4){
    float mx = -1e30f;
    for (int n=0;n<NB_;n++) mx = fmaxf(mx, aligns[tid*NB_+n]);
    float s = 0.f;
    for (int n=0;n<NB_;n++){ float e = __expf(aligns[tid*NB_+n]-mx); attns[tid*NB_+n]=e; s+=e; }
    float inv = 1.f/s;
    for (int n=0;n<NB_;n++) attns[tid*NB_+n] *= inv;
  }
  __syncthreads();

  // tm[p][e] = sum_n attn * mem (fp16 from swizzled LDS); float2 per thread
  unsigned otm;
  {
    int kg = e0>>5, s2 = (e0>>3)&3;
    float2 o = make_float2(0.f,0.f);
    #pragma unroll
    for (int n=0;n<NB_;n++){
      int row = p2*NB_+n;
      float a = attns[row];
      int mt = row>>4, r = row&15;
      int slot = (s2<<4) | ((r ^ s2 ^ ((kg&1)<<2)) & 15);
      int chunk = (mt*4+kg)*64 + slot;
      H2 q; q.u = *(const unsigned*)(mfr + chunk*8 + (e0&7));
      o.x += a*(float)q.h[0];
      o.y += a*(float)q.h[1];
    }
    otm = pk2(o.x, o.y);
    *(unsigned*)(tm_h + ((size_t)g*4+p2)*128 + e0) = otm;   // fp16 tm for K3
  }
  __syncthreads();   // all mfr reads complete

  // write A2 fragments (rows 0..3 = tm kc0-3, stories kc4-7) into mfr[0..4095]
  // frag: chunk = kc*64 + lane2, lane2 = ((k>>3)&3)<<4 | row, halfword j=k&7
  {
    int kc = e0>>5;
    int lane2 = (((e0>>3)&3)<<4) | p2;
    *(unsigned*)(mfr + (kc*64+lane2)*8 + (e0&7)) = otm;
    *(unsigned*)(mfr + ((kc+4)*64+lane2)*8 + (e0&7)) = pk2(sto.x, sto.y);
  }
  __syncthreads();

  // MFMA2: K=256 against [D;E] fragments; rows 4..15 are stale finite fp16 -> discarded
  {
    f32x4 acc0 = (f32x4)(0.f), acc1 = (f32x4)(0.f);
    #pragma unroll
    for (int kc=0;kc<8;kc++){
      FragH af, b0, b1;
      af.u = *(const uint4*)(mfr + (kc*64+lane)*8);
      b0.u = *(const uint4*)(w2frag + ((size_t)((2*w)*8+kc)*64+lane)*8);
      b1.u = *(const uint4*)(w2frag + ((size_t)((2*w+1)*8+kc)*64+lane)*8);
      acc0 = __builtin_amdgcn_mfma_f32_16x16x32_f16(af.h, b0.h, acc0, 0,0,0);
      acc1 = __builtin_amdgcn_mfma_f32_16x16x32_f16(af.h, b1.h, acc1, 0,0,0);
    }
    if (hi16 == 0){
      #pragma unroll
      for (int r=0;r<4;r++){
        int i0 = (2*w)*16+lo16;
        float part = wvec[i0]*tanh_fast(acc0[r] + tf_w[b*128+i0]);
        int i1 = (2*w+1)*16+lo16;
        part += wvec[i1]*tanh_fast(acc1[r] + tf_w[b*128+i1]);
        part += __shfl_xor(part,1);
        part += __shfl_xor(part,2);
        part += __shfl_xor(part,4);
        part += __shfl_xor(part,8);
        if (lo16==0) partial2[w*4+r] = part;
      }
    }
  }
  __syncthreads();
  if (tid<4){
    float ta = partial2[tid]+partial2[4+tid]+partial2[8+tid]+partial2[12+tid];
    int flat = g*4+tid;
    float m = smask[flat];
    talign_w[flat] = (m != 0.0f) ? ta*m : -INFINITY;
  }
}

// ---------------------------------------------------------------------------
// K3: softmax over S=512 + o = sum_s attn*tm (fp16) + uh.
// 256 blocks = (b, e-chunk of 16). Redundant cheap softmax per block;
// inner read as fp16x2/lane for 32B-per-16-lane segments.
// ---------------------------------------------------------------------------
__global__ __launch_bounds__(256) void k3_kernel(
    const float* __restrict__ talign_w, const unsigned short* __restrict__ tm_h,
    const float* __restrict__ uh_w, float* __restrict__ ov_w)
{
  __shared__ float attn[512];
  __shared__ float red[256];
  __shared__ float2 red2[256];
  int bid = blockIdx.x, tid = threadIdx.x;
  int b = bid >> 3, ec = bid & 7;

  float v0 = talign_w[b*512+tid];
  float v1 = talign_w[b*512+256+tid];
  red[tid] = fmaxf(v0,v1);
  __syncthreads();
  for (int s=128;s>0;s>>=1){ if (tid<s) red[tid]=fmaxf(red[tid],red[tid+s]); __syncthreads(); }
  float M = red[0];
  __syncthreads();
  float e0v = __expf(v0-M), e1v = __expf(v1-M);
  red[tid] = e0v+e1v;
  __syncthreads();
  for (int s=128;s>0;s>>=1){ if (tid<s) red[tid]+=red[tid+s]; __syncthreads(); }
  float invZ = 1.f/red[0];
  attn[tid] = e0v*invZ;
  attn[256+tid] = e1v*invZ;
  __syncthreads();

  // o[b][ec*16 + (tid&7)*2 +0/1]: 32 s-groups x 16 s each
  int e = ec*16 + (tid&7)*2;
  int sg = tid>>3;
  const unsigned short* tmb = tm_h + ((size_t)b*512 + sg*16)*128 + e;
  float2 a2 = make_float2(0.f,0.f);
  #pragma unroll 8
  for (int i=0;i<16;i++){
    H2 q; q.u = *(const unsigned*)(tmb + (size_t)i*128);
    float at = attn[sg*16+i];
    a2.x += at*(float)q.h[0];
    a2.y += at*(float)q.h[1];
  }
  red2[tid] = a2;
  __syncthreads();
  for (int s=128;s>=8;s>>=1){
    if (tid<s){ red2[tid].x += red2[tid+s].x; red2[tid].y += red2[tid+s].y; }
    __syncthreads();
  }
  if (tid<8){
    int e2 = ec*16 + tid*2;
    ov_w[b*128+e2]   = red2[tid].x + uh_w[b*128+e2];
    ov_w[b*128+e2+1] = red2[tid].y + uh_w[b*128+e2+1];
  }
}

// ---------------------------------------------------------------------------
// K4: logits[b][j] = sum_e ov[b][e]*R[e][j]
// 313 blocks, j-tile 128 (float2/lane), 4 b-groups of 8; float4 uniform ov.
// ---------------------------------------------------------------------------
__global__ __launch_bounds__(256) void k4_kernel(
    const float* __restrict__ ov_w, const float* __restrict__ R,
    float* __restrict__ out)
{
  int tid = threadIdx.x;
  int j = blockIdx.x*128 + (tid&63)*2;
  if (j >= VOC_) return;
  int bh = tid>>6;                 // 0..3 -> b = bh*8 + bb
  const float* ovb = ov_w + bh*8*128;
  float2 acc[8];
  #pragma unroll
  for (int bb=0;bb<8;bb++) acc[bb]=make_float2(0.f,0.f);
  for (int e=0;e<128;e+=4){
    float2 r0 = *(const float2*)(&R[(size_t)(e+0)*VOC_ + j]);
    float2 r1 = *(const float2*)(&R[(size_t)(e+1)*VOC_ + j]);
    float2 r2 = *(const float2*)(&R[(size_t)(e+2)*VOC_ + j]);
    float2 r3 = *(const float2*)(&R[(size_t)(e+3)*VOC_ + j]);
    #pragma unroll
    for (int bb=0;bb<8;bb++){
      float4 o = *(const float4*)(&ovb[bb*128+e]);
      acc[bb].x += o.x*r0.x + o.y*r1.x + o.z*r2.x + o.w*r3.x;
      acc[bb].y += o.x*r0.y + o.y*r1.y + o.z*r2.y + o.w*r3.y;
    }
  }
  #pragma unroll
  for (int bb=0;bb<8;bb++)
    *(float2*)(&out[(size_t)(bh*8+bb)*VOC_ + j]) = acc[bb];
}

// ---------------------------------------------------------------------------
extern "C" void kernel_launch(void* const* d_in, const int* in_sizes, int n_in,
                              void* d_out, int out_size, void* d_ws, size_t ws_size,
                              hipStream_t stream)
{
  const float* mem    = (const float*)d_in[0];
  const float* stories= (const float*)d_in[1];
  const float* smask  = (const float*)d_in[2];
  const int*   queries= (const int*)d_in[3];
  const int*   keys   = (const int*)d_in[4];
  const float* emb    = (const float*)d_in[5];
  const float* mmask  = (const float*)d_in[6];
  const float* A      = (const float*)d_in[7];
  const float* Bm     = (const float*)d_in[8];
  const float* C      = (const float*)d_in[9];
  const float* vvec   = (const float*)d_in[10];
  const float* D      = (const float*)d_in[11];
  const float* E      = (const float*)d_in[12];
  const float* F      = (const float*)d_in[13];
  const float* wvec   = (const float*)d_in[14];
  const float* H      = (const float*)d_in[15];
  const float* R      = (const float*)d_in[16];
  float* out = (float*)d_out;

  char* ws = (char*)d_ws;
  float* qc_w             = (float*)(ws + 0);         // 16384
  float* tf_w             = (float*)(ws + 16384);     // 16384
  float* uh_w             = (float*)(ws + 32768);     // 16384
  float* kb_w             = (float*)(ws + 49152);     // 10240
  unsigned short* afrag   = (unsigned short*)(ws + 60416);   // 32768
  unsigned short* w2frag  = (unsigned short*)(ws + 93184);   // 65536
  unsigned short* tm_h    = (unsigned short*)(ws + 158720);  // 4194304 (fp16)
  float* talign_w         = (float*)(ws + 4353024);   // 65536
  float* ov_w             = (float*)(ws + 4418560);   // 16384

  prep_kernel<<<76,128,0,stream>>>(queries, keys, emb, mmask, A, Bm, C, D, E, F, H,
                                   qc_w, tf_w, uh_w, kb_w, afrag, w2frag);
  k2_kernel<<<4096,256,0,stream>>>(mem, afrag, kb_w, qc_w, vvec,
                                   stories, w2frag, tf_w, wvec, smask,
                                   tm_h, talign_w);
  k3_kernel<<<256,256,0,stream>>>(talign_w, tm_h, uh_w, ov_w);
  k4_kernel<<<313,256,0,stream>>>(ov_w, R, out);
}

// Round 3
// 368.537 us; speedup vs baseline: 1.0151x; 1.0151x over previous
//
#include <hip/hip_runtime.h>
#include <hip/hip_bf16.h>

// Problem constants
#define B_   32
#define S_   512
#define NB_  20
#define EMB_ 128
#define VOC_ 40000

typedef float f32x4 __attribute__((ext_vector_type(4)));
typedef _Float16 f16x8 __attribute__((ext_vector_type(8)));
typedef __fp16 fp16x2 __attribute__((ext_vector_type(2)));

union FragH { uint4 u; f16x8 h; };
union H2 { fp16x2 h; unsigned u; };

__device__ __forceinline__ unsigned pk2(float a, float b){
  H2 t; t.h = __builtin_amdgcn_cvt_pkrtz(a, b);
  return t.u;
}
__device__ __forceinline__ unsigned short f2h(float x){
  _Float16 h = (_Float16)x;   // RNE
  return __builtin_bit_cast(unsigned short, h);
}
// tanh = 1 - 2/(e^{2x}+1); exp2-form + hw rcp: 6 VALU instr, no IEEE divide.
__device__ __forceinline__ float tanh_fast(float x){
  float xx = fminf(fmaxf(x, -15.f), 15.f);
  float e2 = __builtin_amdgcn_exp2f(xx * 2.8853900817779268f);  // 2*log2(e)
  float r  = __builtin_amdgcn_rcpf(e2 + 1.f);
  return fmaf(-2.f, r, 1.f);
}

// LDS fragment-slot swizzle: element (row,k) -> chunk/halfword
//   mt=row>>4, r=row&15, kg=k>>5, s2=(k>>3)&3, off=k&7
//   slot = s2<<4 | ((r ^ s2 ^ ((kg&1)<<2)) & 15)
//   chunk = (mt*4+kg)*64 + slot ; halfword = chunk*8 + off
// Reader lane l for (mt,kc): s2=l>>4, r=l&15  -> one ds_read_b128.

// ---------------------------------------------------------------------------
// Prep: u, qc=u@C, tf=u@F, uh=u@H, kb=emb[keys]@Bm (fp32),
// plus fp16 B-operand fragments of A (K=128) and [D;E] (K=256).
// ---------------------------------------------------------------------------
__global__ __launch_bounds__(128) void prep_kernel(
    const int* __restrict__ queries, const int* __restrict__ keys,
    const float* __restrict__ emb, const float* __restrict__ mmask,
    const float* __restrict__ A, const float* __restrict__ Bm,
    const float* __restrict__ C, const float* __restrict__ D,
    const float* __restrict__ E, const float* __restrict__ F,
    const float* __restrict__ H,
    float* __restrict__ qc_w, float* __restrict__ tf_w,
    float* __restrict__ uh_w, float* __restrict__ kb_w,
    unsigned short* __restrict__ afrag, unsigned short* __restrict__ w2frag)
{
  int bid = blockIdx.x, tid = threadIdx.x;
  if (bid < 32) {
    __shared__ float ulds[128];
    int b = bid;
    float s = 0.f;
    for (int q=0;q<NB_;q++){
      int tok = queries[b*NB_+q];
      s += emb[tok*128+tid]*mmask[q*128+tid];
    }
    ulds[tid] = s;
    __syncthreads();
    float sq=0.f, sf=0.f, sh=0.f;
    for (int e=0;e<128;e++){
      float uv = ulds[e];
      sq += uv*C[e*128+tid];
      sf += uv*F[e*128+tid];
      sh += uv*H[e*128+tid];
    }
    qc_w[b*128+tid]=sq; tf_w[b*128+tid]=sf; uh_w[b*128+tid]=sh;
  } else if (bid < 52) {
    __shared__ float ek[128];
    int n = bid-32;
    int tok = keys[n];
    ek[tid] = emb[tok*128+tid];
    __syncthreads();
    float s=0.f;
    for (int e=0;e<128;e++) s += ek[e]*Bm[e*128+tid];
    kb_w[n*128+tid] = s;
  } else if (bid < 60) {
    // A fragments: nt=8, kc=4 -> 2048 chunks fp16
    int a = bid-52;
    for (int cc=0;cc<2;cc++){
      int c = (a*128+tid)*2+cc;
      int lane = c&63, kc = (c>>6)&3, nt = c>>8;
      int n2 = nt*16 + (lane&15);
      int k0 = kc*32 + (lane>>4)*8;
      alignas(16) unsigned short t[8];
      #pragma unroll
      for (int j=0;j<8;j++) t[j] = f2h(A[(k0+j)*128+n2]);
      *(uint4*)(afrag + c*8) = *(const uint4*)t;
    }
  } else {
    // W2=[D;E] fragments: nt=8, kc=8 -> 4096 chunks fp16
    int wb = bid-60;
    for (int cc=0;cc<2;cc++){
      int c = (wb*128+tid)*2+cc;
      int lane = c&63, kc = (c>>6)&7, nt = c>>9;
      int n2 = nt*16 + (lane&15);
      int k0 = kc*32 + (lane>>4)*8;
      alignas(16) unsigned short t[8];
      #pragma unroll
      for (int j=0;j<8;j++){
        int k = k0+j;
        float x = (k<128) ? D[k*128+n2] : E[(k-128)*128+n2];
        t[j] = f2h(x);
      }
      *(uint4*)(w2frag + c*8) = *(const uint4*)t;
    }
  }
}

// ---------------------------------------------------------------------------
// K2 (merged): 4 (b,s) pairs/block.
// Phase 1: M=80,K=128,N=128 fp16 MFMA (ia) -> intr align/softmax -> tm.
// Phase 2: reuse LDS: A2=[tm|stories] (K=256) @ [D;E] -> talign.
// ---------------------------------------------------------------------------
__global__ __launch_bounds__(256) void k2_kernel(
    const float* __restrict__ mem, const unsigned short* __restrict__ afrag,
    const float* __restrict__ kb_w, const float* __restrict__ qc_w,
    const float* __restrict__ vvec,
    const float* __restrict__ stories, const unsigned short* __restrict__ w2frag,
    const float* __restrict__ tf_w, const float* __restrict__ wvec,
    const float* __restrict__ smask,
    unsigned short* __restrict__ tm_h, float* __restrict__ talign_w)
{
  __shared__ unsigned short mfr[5*4*64*8];   // 20KB; first 8KB reused as A2 frags
  __shared__ float alignP[4*80];
  __shared__ float aligns[80];
  __shared__ float attns[80];
  __shared__ float partial2[16];

  int g = blockIdx.x, tid = threadIdx.x;
  int b = g >> 7;   // 128 blocks per batch element

  int p2 = tid>>6, e0 = (tid&63)*2;
  float2 sto = *(const float2*)(stories + ((size_t)(g*4+p2))*128 + e0);

  // ---- stage: hoisted swizzle addressing ----
  // k = (tid&31)*4 invariant; row = (tid>>5) + 8*it; mt = it>>1; r alternates r0, r0^8
  {
    int kq = (tid&31)*4;
    int kgs = kq>>5, s2s = (kq>>3)&3, offs = kq&7;
    int r0 = tid>>5;
    int cbs = s2s ^ ((kgs&1)<<2);
    int slot_e = (s2s<<4) | ((r0 ^ cbs) & 15);
    int slot_o = (s2s<<4) | (((r0^8) ^ cbs) & 15);
    unsigned addr_e = (unsigned)((kgs*64 + slot_e)*16 + offs*2);
    unsigned addr_o = (unsigned)((kgs*64 + slot_o)*16 + offs*2);
    const float4* gm = (const float4*)(mem) + (size_t)g*2560 + tid;
    #pragma unroll
    for (int mt=0; mt<5; ++mt){
      float4 d0 = gm[(2*mt)*256];
      float4 d1 = gm[(2*mt+1)*256];
      *(uint2*)((char*)mfr + addr_e + mt*4096) = make_uint2(pk2(d0.x,d0.y), pk2(d0.z,d0.w));
      *(uint2*)((char*)mfr + addr_o + mt*4096) = make_uint2(pk2(d1.x,d1.y), pk2(d1.z,d1.w));
    }
  }
  __syncthreads();

  int w = tid>>6, lane = tid&63;
  int lo16 = lane & 15, hi16 = lane >> 4;

  {
    f32x4 acc[5][2];
    #pragma unroll
    for (int mt=0;mt<5;mt++){ acc[mt][0]=(f32x4)(0.f); acc[mt][1]=(f32x4)(0.f); }

    #pragma unroll
    for (int kc=0;kc<4;kc++){
      FragH b0, b1;
      b0.u = *(const uint4*)(afrag + ((size_t)((2*w)*4+kc)*64 + lane)*8);
      b1.u = *(const uint4*)(afrag + ((size_t)((2*w+1)*4+kc)*64 + lane)*8);
      int slot = (hi16<<4) | ((lo16 ^ hi16 ^ ((kc&1)<<2)) & 15);
      #pragma unroll
      for (int mt=0;mt<5;mt++){
        FragH a;
        a.u = *(const uint4*)(mfr + ((mt*4+kc)*64 + slot)*8);
        acc[mt][0] = __builtin_amdgcn_mfma_f32_16x16x32_f16(a.h, b0.h, acc[mt][0], 0,0,0);
        acc[mt][1] = __builtin_amdgcn_mfma_f32_16x16x32_f16(a.h, b1.h, acc[mt][1], 0,0,0);
      }
    }

    // epilogue: align[row] = sum_i v_i * tanh(ia + kb[n,i] + qc[b,i])
    int i0 = w*32 + lo16, i1 = i0 + 16;
    float qc0 = qc_w[b*128+i0], qc1 = qc_w[b*128+i1];
    float vv0 = vvec[i0],       vv1 = vvec[i1];
    const float* kb0 = kb_w + i0;
    #pragma unroll
    for (int mt=0;mt<5;mt++){
      #pragma unroll
      for (int r=0;r<4;r++){
        unsigned row = mt*16 + hi16*4 + r;
        unsigned p = row/20u;
        unsigned n = row - p*20u;
        float z0 = acc[mt][0][r] + kb0[n*128]    + qc0;
        float z1 = acc[mt][1][r] + kb0[n*128+16] + qc1;
        float part = vv0*tanh_fast(z0) + vv1*tanh_fast(z1);
        part += __shfl_xor(part, 1);
        part += __shfl_xor(part, 2);
        part += __shfl_xor(part, 4);
        part += __shfl_xor(part, 8);
        if (lo16 == 0) alignP[w*80+row] = part;
      }
    }
  }
  __syncthreads();
  if (tid < 80){
    aligns[tid] = alignP[tid] + alignP[80+tid] + alignP[160+tid] + alignP[240+tid];
  }
  __syncthreads();
  if (tid < 4){
    float mx = -1e30f;
    for (int n=0;n<NB_;n++) mx = fmaxf(mx, aligns[tid*NB_+n]);
    float s = 0.f;
    for (int n=0;n<NB_;n++){ float e = __expf(aligns[tid*NB_+n]-mx); attns[tid*NB_+n]=e; s+=e; }
    float inv = 1.f/s;
    for (int n=0;n<NB_;n++) attns[tid*NB_+n] *= inv;
  }
  __syncthreads();

  // ---- tm[p][e] = sum_n attn*mem : wave-uniform p2 -> compile-time row consts ----
  unsigned otm;
  {
    int kg = e0>>5, s2 = (e0>>3)&3;
    int cb = s2 ^ ((kg&1)<<2);
    unsigned base = (unsigned)((kg*64 + (s2<<4))*16 + (e0&7)*2);
    float2 o = make_float2(0.f,0.f);
    #define TM_STEP(ROW) { \
      H2 q; q.u = *(const unsigned*)((const char*)mfr + base + (((ROW)>>4)*4096) + ((((ROW)&15) ^ cb) & 15)*16); \
      float a = attns[(ROW)]; \
      o.x += a*(float)q.h[0]; \
      o.y += a*(float)q.h[1]; }
    #define TM_20(P) { \
      TM_STEP((P)*20+0)  TM_STEP((P)*20+1)  TM_STEP((P)*20+2)  TM_STEP((P)*20+3)  \
      TM_STEP((P)*20+4)  TM_STEP((P)*20+5)  TM_STEP((P)*20+6)  TM_STEP((P)*20+7)  \
      TM_STEP((P)*20+8)  TM_STEP((P)*20+9)  TM_STEP((P)*20+10) TM_STEP((P)*20+11) \
      TM_STEP((P)*20+12) TM_STEP((P)*20+13) TM_STEP((P)*20+14) TM_STEP((P)*20+15) \
      TM_STEP((P)*20+16) TM_STEP((P)*20+17) TM_STEP((P)*20+18) TM_STEP((P)*20+19) }
    switch(p2){
      case 0: TM_20(0) break;
      case 1: TM_20(1) break;
      case 2: TM_20(2) break;
      default: TM_20(3) break;
    }
    otm = pk2(o.x, o.y);
    *(unsigned*)(tm_h + ((size_t)g*4+p2)*128 + e0) = otm;   // fp16 tm for K3
  }
  __syncthreads();   // all mfr reads complete

  // write A2 fragments (rows 0..3 = tm kc0-3, stories kc4-7) into mfr[0..4095]
  {
    int kc = e0>>5;
    int lane2 = (((e0>>3)&3)<<4) | p2;
    *(unsigned*)(mfr + (kc*64+lane2)*8 + (e0&7)) = otm;
    *(unsigned*)(mfr + ((kc+4)*64+lane2)*8 + (e0&7)) = pk2(sto.x, sto.y);
  }
  __syncthreads();

  // MFMA2: K=256 against [D;E]; rows 4..15 stale finite fp16 -> discarded
  {
    f32x4 acc0 = (f32x4)(0.f), acc1 = (f32x4)(0.f);
    #pragma unroll
    for (int kc=0;kc<8;kc++){
      FragH af, b0, b1;
      af.u = *(const uint4*)(mfr + (kc*64+lane)*8);
      b0.u = *(const uint4*)(w2frag + ((size_t)((2*w)*8+kc)*64+lane)*8);
      b1.u = *(const uint4*)(w2frag + ((size_t)((2*w+1)*8+kc)*64+lane)*8);
      acc0 = __builtin_amdgcn_mfma_f32_16x16x32_f16(af.h, b0.h, acc0, 0,0,0);
      acc1 = __builtin_amdgcn_mfma_f32_16x16x32_f16(af.h, b1.h, acc1, 0,0,0);
    }
    if (hi16 == 0){
      #pragma unroll
      for (int r=0;r<4;r++){
        int i0 = (2*w)*16+lo16;
        float part = wvec[i0]*tanh_fast(acc0[r] + tf_w[b*128+i0]);
        int i1 = (2*w+1)*16+lo16;
        part += wvec[i1]*tanh_fast(acc1[r] + tf_w[b*128+i1]);
        part += __shfl_xor(part,1);
        part += __shfl_xor(part,2);
        part += __shfl_xor(part,4);
        part += __shfl_xor(part,8);
        if (lo16==0) partial2[w*4+r] = part;
      }
    }
  }
  __syncthreads();
  if (tid<4){
    float ta = partial2[tid]+partial2[4+tid]+partial2[8+tid]+partial2[12+tid];
    int flat = g*4+tid;
    float m = smask[flat];
    talign_w[flat] = (m != 0.0f) ? ta*m : -INFINITY;
  }
}

// ---------------------------------------------------------------------------
// K3: softmax over S=512 + o = sum_s attn*tm (fp16) + uh.
// 256 blocks = (b, e-chunk of 16).
// ---------------------------------------------------------------------------
__global__ __launch_bounds__(256) void k3_kernel(
    const float* __restrict__ talign_w, const unsigned short* __restrict__ tm_h,
    const float* __restrict__ uh_w, float* __restrict__ ov_w)
{
  __shared__ float attn[512];
  __shared__ float red[256];
  __shared__ float2 red2[256];
  int bid = blockIdx.x, tid = threadIdx.x;
  int b = bid >> 3, ec = bid & 7;

  float v0 = talign_w[b*512+tid];
  float v1 = talign_w[b*512+256+tid];
  red[tid] = fmaxf(v0,v1);
  __syncthreads();
  for (int s=128;s>0;s>>=1){ if (tid<s) red[tid]=fmaxf(red[tid],red[tid+s]); __syncthreads(); }
  float M = red[0];
  __syncthreads();
  float e0v = __expf(v0-M), e1v = __expf(v1-M);
  red[tid] = e0v+e1v;
  __syncthreads();
  for (int s=128;s>0;s>>=1){ if (tid<s) red[tid]+=red[tid+s]; __syncthreads(); }
  float invZ = 1.f/red[0];
  attn[tid] = e0v*invZ;
  attn[256+tid] = e1v*invZ;
  __syncthreads();

  int e = ec*16 + (tid&7)*2;
  int sg = tid>>3;
  const unsigned short* tmb = tm_h + ((size_t)b*512 + sg*16)*128 + e;
  float2 a2 = make_float2(0.f,0.f);
  #pragma unroll 8
  for (int i=0;i<16;i++){
    H2 q; q.u = *(const unsigned*)(tmb + (size_t)i*128);
    float at = attn[sg*16+i];
    a2.x += at*(float)q.h[0];
    a2.y += at*(float)q.h[1];
  }
  red2[tid] = a2;
  __syncthreads();
  for (int s=128;s>=8;s>>=1){
    if (tid<s){ red2[tid].x += red2[tid+s].x; red2[tid].y += red2[tid+s].y; }
    __syncthreads();
  }
  if (tid<8){
    int e2 = ec*16 + tid*2;
    ov_w[b*128+e2]   = red2[tid].x + uh_w[b*128+e2];
    ov_w[b*128+e2+1] = red2[tid].y + uh_w[b*128+e2+1];
  }
}

// ---------------------------------------------------------------------------
// K4: logits[b][j] = sum_e ov[b][e]*R[e][j]
// ---------------------------------------------------------------------------
__global__ __launch_bounds__(256) void k4_kernel(
    const float* __restrict__ ov_w, const float* __restrict__ R,
    float* __restrict__ out)
{
  int tid = threadIdx.x;
  int j = blockIdx.x*128 + (tid&63)*2;
  if (j >= VOC_) return;
  int bh = tid>>6;                 // 0..3 -> b = bh*8 + bb
  const float* ovb = ov_w + bh*8*128;
  float2 acc[8];
  #pragma unroll
  for (int bb=0;bb<8;bb++) acc[bb]=make_float2(0.f,0.f);
  for (int e=0;e<128;e+=4){
    float2 r0 = *(const float2*)(&R[(size_t)(e+0)*VOC_ + j]);
    float2 r1 = *(const float2*)(&R[(size_t)(e+1)*VOC_ + j]);
    float2 r2 = *(const float2*)(&R[(size_t)(e+2)*VOC_ + j]);
    float2 r3 = *(const float2*)(&R[(size_t)(e+3)*VOC_ + j]);
    #pragma unroll
    for (int bb=0;bb<8;bb++){
      float4 o = *(const float4*)(&ovb[bb*128+e]);
      acc[bb].x += o.x*r0.x + o.y*r1.x + o.z*r2.x + o.w*r3.x;
      acc[bb].y += o.x*r0.y + o.y*r1.y + o.z*r2.y + o.w*r3.y;
    }
  }
  #pragma unroll
  for (int bb=0;bb<8;bb++)
    *(float2*)(&out[(size_t)(bh*8+bb)*VOC_ + j]) = acc[bb];
}

// ---------------------------------------------------------------------------
extern "C" void kernel_launch(void* const* d_in, const int* in_sizes, int n_in,
                              void* d_out, int out_size, void* d_ws, size_t ws_size,
                              hipStream_t stream)
{
  const float* mem    = (const float*)d_in[0];
  const float* stories= (const float*)d_in[1];
  const float* smask  = (const float*)d_in[2];
  const int*   queries= (const int*)d_in[3];
  const int*   keys   = (const int*)d_in[4];
  const float* emb    = (const float*)d_in[5];
  const float* mmask  = (const float*)d_in[6];
  const float* A      = (const float*)d_in[7];
  const float* Bm     = (const float*)d_in[8];
  const float* C      = (const float*)d_in[9];
  const float* vvec   = (const float*)d_in[10];
  const float* D      = (const float*)d_in[11];
  const float* E      = (const float*)d_in[12];
  const float* F      = (const float*)d_in[13];
  const float* wvec   = (const float*)d_in[14];
  const float* H      = (const float*)d_in[15];
  const float* R      = (const float*)d_in[16];
  float* out = (float*)d_out;

  char* ws = (char*)d_ws;
  float* qc_w             = (float*)(ws + 0);         // 16384
  float* tf_w             = (float*)(ws + 16384);     // 16384
  float* uh_w             = (float*)(ws + 32768);     // 16384
  float* kb_w             = (float*)(ws + 49152);     // 10240
  unsigned short* afrag   = (unsigned short*)(ws + 60416);   // 32768
  unsigned short* w2frag  = (unsigned short*)(ws + 93184);   // 65536
  unsigned short* tm_h    = (unsigned short*)(ws + 158720);  // 4194304 (fp16)
  float* talign_w         = (float*)(ws + 4353024);   // 65536
  float* ov_w             = (float*)(ws + 4418560);   // 16384

  prep_kernel<<<76,128,0,stream>>>(queries, keys, emb, mmask, A, Bm, C, D, E, F, H,
                                   qc_w, tf_w, uh_w, kb_w, afrag, w2frag);
  k2_kernel<<<4096,256,0,stream>>>(mem, afrag, kb_w, qc_w, vvec,
                                   stories, w2frag, tf_w, wvec, smask,
                                   tm_h, talign_w);
  k3_kernel<<<256,256,0,stream>>>(talign_w, tm_h, uh_w, ov_w);
  k4_kernel<<<313,256,0,stream>>>(ov_w, R, out);
}